// Round 11
// baseline (637.205 us; speedup 1.0000x reference)
//
#include <hip/hip_runtime.h>
#include <stdint.h>

// Problem constants
#define BN 4
#define SN 2048
#define DN 512
#define HN 8
#define LN 4
#define FN 2048
#define MN (BN * SN)        // 8192 rows
#define TD (3 * DN)         // 1536

typedef __attribute__((ext_vector_type(8))) __bf16 bf16x8;
typedef __attribute__((ext_vector_type(4))) float f32x4;
typedef __attribute__((ext_vector_type(8))) unsigned short ushortx8;

static __device__ __forceinline__ unsigned short f2bf(float f) {
    return __builtin_bit_cast(unsigned short, (__bf16)f);   // RNE via v_cvt
}
static __device__ __forceinline__ float bf2f(unsigned short h) {
    return __builtin_bit_cast(float, (uint32_t)h << 16);
}

// async global->LDS, 16B per lane; LDS dest = wave-uniform base + lane*16
static __device__ __forceinline__ void gload16(const void* g, void* l) {
    __builtin_amdgcn_global_load_lds(
        (const __attribute__((address_space(1))) void*)g,
        (__attribute__((address_space(3))) void*)l, 16, 0, 0);
}

// ---------------- fused f32 -> bf16 cast for all weights + input ----------
__global__ __launch_bounds__(256) void k_cvt_all(const float* __restrict__ Wqkv,
                                                 const float* __restrict__ Wo,
                                                 const float* __restrict__ W1,
                                                 const float* __restrict__ W2,
                                                 const float* __restrict__ te,
                                                 unsigned short* __restrict__ wqkv_b,
                                                 unsigned short* __restrict__ wo_b,
                                                 unsigned short* __restrict__ w1_b,
                                                 unsigned short* __restrict__ w2_b,
                                                 unsigned short* __restrict__ xb) {
    constexpr int G0 = LN * TD * DN / 4;
    constexpr int G1 = G0 + LN * DN * DN / 4;
    constexpr int G2 = G1 + LN * FN * DN / 4;
    constexpr int G3 = G2 + LN * DN * FN / 4;
    constexpr int G4 = G3 + MN * DN / 4;
    int i = blockIdx.x * blockDim.x + threadIdx.x;
    int stride = gridDim.x * blockDim.x;
    for (; i < G4; i += stride) {
        const float* s; unsigned short* d; int j;
        if (i < G0)      { s = Wqkv; d = wqkv_b; j = i; }
        else if (i < G1) { s = Wo;   d = wo_b;   j = i - G0; }
        else if (i < G2) { s = W1;   d = w1_b;   j = i - G1; }
        else if (i < G3) { s = W2;   d = w2_b;   j = i - G2; }
        else             { s = te;   d = xb;     j = i - G3; }
        float4 v = ((const float4*)s)[j];
        ushort4 o;
        o.x = f2bf(v.x); o.y = f2bf(v.y); o.z = f2bf(v.z); o.w = f2bf(v.w);
        ((ushort4*)d)[j] = o;
    }
}

// ---------------- GEMM: C[M,N] = A[M,K] @ B[N,K]^T + bias, bf16 out ------
// T3-minimum 2-phase: double-buffered LDS (BK=32), next tile's
// global_load_lds issued BEFORE current tile's compute, ONE barrier/step.
// Granule XOR swizzle for 64B rows: granule = slot ^ (row&3).
// MODE 1: bf16; MODE 2: bf16 + ReLU
template <int MODE, int BNT>
__global__ __launch_bounds__(256) void k_gemm(const unsigned short* __restrict__ A,
                                              const unsigned short* __restrict__ B,
                                              const float* __restrict__ bias,
                                              unsigned short* __restrict__ Cb,
                                              int M, int N, int K, int GX) {
    __shared__ __align__(16) unsigned short As[2][128][32];   // 16KB
    __shared__ __align__(16) unsigned short Bs[2][BNT][32];   // 16/8KB
    constexpr int NFR = BNT / 32;        // n-frags per wave (4 or 2)
    constexpr int BCH = BNT / 16;        // B chunks (8 or 4)

    const int t = threadIdx.x;
    const int lane = t & 63;
    const int wid = t >> 6;
    const int wm = wid >> 1, wn = wid & 1;
    const int lr = lane & 15;
    const int lg = lane >> 4;
    const int l3 = lr & 3;

    // XCD-aware bijective swizzle (nwg % 8 == 0 for all our shapes)
    const int nwg = gridDim.x;
    const int bid = blockIdx.x;
    const int swz = (bid & 7) * (nwg >> 3) + (bid >> 3);
    const int bx = swz % GX;
    const int by = swz / GX;

    const size_t rowA = (size_t)by * 128;
    const size_t rowB = (size_t)bx * BNT;
    const unsigned short* Ab = A + rowA * K;
    const unsigned short* Bb = B + rowB * K;

    // staging: chunk = 16 rows x 32 cols (1KB); lane -> row 16c+(lane>>2),
    // LDS slot lane&3; global granule = slot ^ (row&3)  [inverse swizzle]
    const int srow = lane >> 2;                 // 0..15
    const int sgran = (lane & 3) ^ (srow & 3);

    f32x4 acc[4][NFR] = {};

    const int nit = K >> 5;

    // prologue: stage tile 0 into buf 0
#pragma unroll
    for (int j = 0; j < 2; ++j) {               // A: 8 chunks over 4 waves
        const int c = wid * 2 + j;
        gload16(Ab + (size_t)(16 * c + srow) * K + sgran * 8, &As[0][16 * c][0]);
    }
#pragma unroll
    for (int j = 0; j < BCH / 4; ++j) {         // B: BCH chunks over 4 waves
        const int c = wid * (BCH / 4) + j;
        gload16(Bb + (size_t)(16 * c + srow) * K + sgran * 8, &Bs[0][16 * c][0]);
    }
    __syncthreads();

    for (int it = 0; it < nit; ++it) {
        const int cur = it & 1;
        if (it + 1 < nit) {                     // issue next-tile loads early
            const int k0 = (it + 1) << 5;
#pragma unroll
            for (int j = 0; j < 2; ++j) {
                const int c = wid * 2 + j;
                gload16(Ab + (size_t)(16 * c + srow) * K + k0 + sgran * 8,
                        &As[cur ^ 1][16 * c][0]);
            }
#pragma unroll
            for (int j = 0; j < BCH / 4; ++j) {
                const int c = wid * (BCH / 4) + j;
                gload16(Bb + (size_t)(16 * c + srow) * K + k0 + sgran * 8,
                        &Bs[cur ^ 1][16 * c][0]);
            }
        }

        // compute current tile (loads for next tile in flight)
        const int gp = (lg ^ l3) * 8;
        bf16x8 af[4], bfr[NFR];
#pragma unroll
        for (int mi = 0; mi < 4; ++mi)
            af[mi] = *(const bf16x8*)&As[cur][wm * 64 + mi * 16 + lr][gp];
#pragma unroll
        for (int ni = 0; ni < NFR; ++ni)
            bfr[ni] = *(const bf16x8*)&Bs[cur][wn * (BNT / 2) + ni * 16 + lr][gp];
#pragma unroll
        for (int mi = 0; mi < 4; ++mi)
#pragma unroll
            for (int ni = 0; ni < NFR; ++ni)
                acc[mi][ni] = __builtin_amdgcn_mfma_f32_16x16x32_bf16(
                    af[mi], bfr[ni], acc[mi][ni], 0, 0, 0);

        __syncthreads();   // drains vmcnt (stage done) + lgkm; buf swap safe
    }

    float bv[NFR];
#pragma unroll
    for (int ni = 0; ni < NFR; ++ni)
        bv[ni] = bias[(int)rowB + wn * (BNT / 2) + ni * 16 + lr];

#pragma unroll
    for (int mi = 0; mi < 4; ++mi) {
#pragma unroll
        for (int ni = 0; ni < NFR; ++ni) {
            int col = (int)rowB + wn * (BNT / 2) + ni * 16 + lr;
            int row0 = (int)rowA + wm * 64 + mi * 16 + lg * 4;
#pragma unroll
            for (int r = 0; r < 4; ++r) {
                float v = acc[mi][ni][r] + bv[ni];
                if (MODE == 2) v = fmaxf(v, 0.f);
                Cb[(size_t)(row0 + r) * N + col] = f2bf(v);
            }
        }
    }
}

// ---------------- MFMA flash attention, QBLK=64, no-max softmax -----------
// Round-7 structure (best measured): reg-staged K/V, XOR-swizzled
// conflict-free LDS, 4 waves, 1024 blocks, 40KB = 4 blocks/CU.
__global__ __launch_bounds__(256) void k_attn(const unsigned short* __restrict__ qkv,
                                              const int* __restrict__ spk,
                                              unsigned short* __restrict__ o) {
    __shared__ __align__(16) unsigned short Ks[2][64][64];
    __shared__ __align__(16) unsigned short Vt[2][64][64];   // Vt[d][k]
    __shared__ __align__(16) unsigned short Ps[4][16][64];

    const int t = threadIdx.x;
    const int lane = t & 63;
    const int w = t >> 6;
    const int lr = lane & 15;
    const int lg = lane >> 4;
    const int l7 = lr & 7;

    const int wg = blockIdx.x;
    const int inner = wg >> 3;
    const int bh = 4 * (wg & 7) + (inner & 3);        // XCD owns 4 (b,h) cols
    const int qtile = (SN / 64 - 1) - (inner >> 2);   // heavy tiles first
    const int b = bh >> 3;
    const int h = bh & 7;
    const int qb = qtile * 64;

    const size_t base = (size_t)b * SN * TD;
    const unsigned short* kg = qkv + base + DN + h * 64;
    const unsigned short* vg = qkv + base + 2 * DN + h * 64;

    // Q fragments (A-operand), pre-scaled by 1/sqrt(64)*log2(e)
    const float SCL = 0.125f * 1.4426950408889634f;
    const unsigned short* qptr = qkv + base + (size_t)(qb + w * 16 + lr) * TD + h * 64;
    bf16x8 aq0 = *(const bf16x8*)(qptr + lg * 8);
    bf16x8 aq1 = *(const bf16x8*)(qptr + 32 + lg * 8);
#pragma unroll
    for (int j = 0; j < 8; ++j) {
        aq0[j] = (__bf16)((float)aq0[j] * SCL);
        aq1[j] = (__bf16)((float)aq1[j] * SCL);
    }

    int sqr[4], qrow[4];
#pragma unroll
    for (int r = 0; r < 4; ++r) {
        qrow[r] = qb + w * 16 + lg * 4 + r;
        sqr[r] = spk[b * SN + qrow[r]];
    }

    // staging coords
    const int kr0 = t >> 3;              // 0..31
    const int kgr = ((t & 7) ^ (kr0 & 7)) * 8;   // swizzled granule
    const int vrow = t & 63;
    const int vd0 = (t >> 6) * 16;

    // prefetch + stage tile 0
    uint4 kra = *(const uint4*)&kg[(size_t)kr0 * TD + (t & 7) * 8];
    uint4 krb = *(const uint4*)&kg[(size_t)(kr0 + 32) * TD + (t & 7) * 8];
    ushortx8 vra = *(const ushortx8*)&vg[(size_t)vrow * TD + vd0];
    ushortx8 vrb = *(const ushortx8*)&vg[(size_t)vrow * TD + vd0 + 8];
    *(uint4*)&Ks[0][kr0][kgr] = kra;
    *(uint4*)&Ks[0][kr0 + 32][kgr] = krb;
#pragma unroll
    for (int j = 0; j < 8; ++j) {
        const int vc0 = (((vrow >> 3) ^ j) << 3) + (vrow & 7); // (vd0+j)&7 == j
        Vt[0][vd0 + j][vc0] = vra[j];
        Vt[0][vd0 + 8 + j][vc0] = vrb[j];
    }

    float lsum[4] = {0.f, 0.f, 0.f, 0.f};   // per-lane partial softmax denom
    f32x4 acc_o[4] = {};

    const int ntiles = qtile + 1;
    for (int it = 0; it < ntiles; ++it) {
        const int k0 = it * 64;
        const int cur = it & 1;
        __syncthreads();   // buf[cur] staged & visible; buf[cur^1] free

        const bool nx = (it + 1 < ntiles);
        if (nx) {          // prefetch next tile into regs (T14)
            const int kn = k0 + 64;
            kra = *(const uint4*)&kg[(size_t)(kn + kr0) * TD + (t & 7) * 8];
            krb = *(const uint4*)&kg[(size_t)(kn + kr0 + 32) * TD + (t & 7) * 8];
            vra = *(const ushortx8*)&vg[(size_t)(kn + vrow) * TD + vd0];
            vrb = *(const ushortx8*)&vg[(size_t)(kn + vrow) * TD + vd0 + 8];
        }
        int skr[4];
#pragma unroll
        for (int ni = 0; ni < 4; ++ni) skr[ni] = spk[b * SN + k0 + 16 * ni + lr];

        // QK^T (pre-scaled): S[16q][64k] in log2 domain
        f32x4 sc4[4] = {};
        __builtin_amdgcn_s_setprio(1);
#pragma unroll
        for (int ni = 0; ni < 4; ++ni) {
            bf16x8 bk0 = *(const bf16x8*)&Ks[cur][16 * ni + lr][(lg ^ l7) * 8];
            bf16x8 bk1 = *(const bf16x8*)&Ks[cur][16 * ni + lr][((lg + 4) ^ l7) * 8];
            sc4[ni] = __builtin_amdgcn_mfma_f32_16x16x32_bf16(aq0, bk0, sc4[ni], 0, 0, 0);
            sc4[ni] = __builtin_amdgcn_mfma_f32_16x16x32_bf16(aq1, bk1, sc4[ni], 0, 0, 0);
        }
        __builtin_amdgcn_s_setprio(0);

        // p = allow ? exp2(s) : 0 ; accumulate per-lane denom; stash bf16 P
        const bool diag = (it == ntiles - 1);
#pragma unroll
        for (int ni = 0; ni < 4; ++ni) {
#pragma unroll
            for (int r = 0; r < 4; ++r) {
                bool allow = (skr[ni] == sqr[r]);
                if (diag) allow = allow && (16 * ni + lr <= w * 16 + lg * 4 + r);
                float p = allow ? __builtin_amdgcn_exp2f(sc4[ni][r]) : 0.f;
                lsum[r] += p;
                const int q7 = (lg * 4 + r) & 7;
                const int pg = ((2 * ni + (lr >> 3)) ^ q7) * 8 + l7;
                Ps[w][lg * 4 + r][pg] = f2bf(p);
            }
        }

        // PV: O[16q][64d] += P[16q][64k] @ V[64k][64d]
        bf16x8 ap0 = *(const bf16x8*)&Ps[w][lr][(lg ^ l7) * 8];
        bf16x8 ap1 = *(const bf16x8*)&Ps[w][lr][((lg + 4) ^ l7) * 8];
        __builtin_amdgcn_s_setprio(1);
#pragma unroll
        for (int ni = 0; ni < 4; ++ni) {
            bf16x8 bv0 = *(const bf16x8*)&Vt[cur][16 * ni + lr][(lg ^ l7) * 8];
            bf16x8 bv1 = *(const bf16x8*)&Vt[cur][16 * ni + lr][((lg + 4) ^ l7) * 8];
            acc_o[ni] = __builtin_amdgcn_mfma_f32_16x16x32_bf16(ap0, bv0, acc_o[ni], 0, 0, 0);
            acc_o[ni] = __builtin_amdgcn_mfma_f32_16x16x32_bf16(ap1, bv1, acc_o[ni], 0, 0, 0);
        }
        __builtin_amdgcn_s_setprio(0);

        if (nx) {          // write prefetched tile into the other buffer
            const int nb = cur ^ 1;
            *(uint4*)&Ks[nb][kr0][kgr] = kra;
            *(uint4*)&Ks[nb][kr0 + 32][kgr] = krb;
#pragma unroll
            for (int j = 0; j < 8; ++j) {
                const int vc0 = (((vrow >> 3) ^ j) << 3) + (vrow & 7);
                Vt[nb][vd0 + j][vc0] = vra[j];
                Vt[nb][vd0 + 8 + j][vc0] = vrb[j];
            }
        }
    }

    // reduce denom across the 16 k-lanes (lane bits 0..3), then write O
#pragma unroll
    for (int r = 0; r < 4; ++r) {
        float s = lsum[r];
        s += __shfl_xor(s, 1);
        s += __shfl_xor(s, 2);
        s += __shfl_xor(s, 4);
        s += __shfl_xor(s, 8);
        float inv = 1.f / s;
#pragma unroll
        for (int ni = 0; ni < 4; ++ni) {
            int d = 16 * ni + lr;
            o[(size_t)(b * SN + qrow[r]) * DN + h * 64 + d] = f2bf(acc_o[ni][r] * inv);
        }
    }
}

// ---------------- residual add + LayerNorm (wave per row of 512) ----------
// bf16 residual stream; optional f32 final output.
template <bool XF32>
__global__ __launch_bounds__(256) void k_add_ln(const void* __restrict__ xin_,
                                                const unsigned short* __restrict__ dl,
                                                const float* __restrict__ g,
                                                const float* __restrict__ bta,
                                                unsigned short* __restrict__ xb,
                                                float* __restrict__ fout) {
    const int row = blockIdx.x * 4 + (threadIdx.x >> 6);
    const int lane = threadIdx.x & 63;
    const size_t off = (size_t)row * DN + lane * 8;
    const int c0 = lane * 8;

    float v[8];
    if (XF32) {
        const float* xin = (const float*)xin_;
        float4 a0 = *(const float4*)&xin[off];
        float4 a1 = *(const float4*)&xin[off + 4];
        v[0] = a0.x; v[1] = a0.y; v[2] = a0.z; v[3] = a0.w;
        v[4] = a1.x; v[5] = a1.y; v[6] = a1.z; v[7] = a1.w;
    } else {
        ushortx8 xa = *(const ushortx8*)&((const unsigned short*)xin_)[off];
#pragma unroll
        for (int i = 0; i < 8; ++i) v[i] = bf2f(xa[i]);
    }
    ushortx8 dd = *(const ushortx8*)&dl[off];
#pragma unroll
    for (int i = 0; i < 8; ++i) v[i] += bf2f(dd[i]);

    float s1 = 0.f, s2 = 0.f;
#pragma unroll
    for (int i = 0; i < 8; ++i) { s1 += v[i]; s2 += v[i] * v[i]; }
#pragma unroll
    for (int msk = 32; msk; msk >>= 1) {
        s1 += __shfl_xor(s1, msk);
        s2 += __shfl_xor(s2, msk);
    }
    const float mean = s1 * (1.f / 512.f);
    const float var = s2 * (1.f / 512.f) - mean * mean;
    const float rs = rsqrtf(var + 1e-5f);

    float4 g0 = *(const float4*)&g[c0];
    float4 g1 = *(const float4*)&g[c0 + 4];
    float4 b0 = *(const float4*)&bta[c0];
    float4 b1 = *(const float4*)&bta[c0 + 4];
    float gg[8] = {g0.x, g0.y, g0.z, g0.w, g1.x, g1.y, g1.z, g1.w};
    float bb[8] = {b0.x, b0.y, b0.z, b0.w, b1.x, b1.y, b1.z, b1.w};

    float y[8];
    ushortx8 ub;
#pragma unroll
    for (int i = 0; i < 8; ++i) {
        y[i] = (v[i] - mean) * rs * gg[i] + bb[i];
        ub[i] = f2bf(y[i]);
    }
    *(ushortx8*)&xb[off] = ub;
    if (fout) {
        *(float4*)&fout[off] = make_float4(y[0], y[1], y[2], y[3]);
        *(float4*)&fout[off + 4] = make_float4(y[4], y[5], y[6], y[7]);
    }
}

extern "C" void kernel_launch(void* const* d_in, const int* in_sizes, int n_in,
                              void* d_out, int out_size, void* d_ws, size_t ws_size,
                              hipStream_t stream) {
    const float* te   = (const float*)d_in[0];
    const float* Wqkv = (const float*)d_in[1];
    const float* bqkv = (const float*)d_in[2];
    const float* Wo   = (const float*)d_in[3];
    const float* bo   = (const float*)d_in[4];
    const float* W1   = (const float*)d_in[5];
    const float* b1   = (const float*)d_in[6];
    const float* W2   = (const float*)d_in[7];
    const float* b2   = (const float*)d_in[8];
    const float* g1   = (const float*)d_in[9];
    const float* be1  = (const float*)d_in[10];
    const float* g2   = (const float*)d_in[11];
    const float* be2  = (const float*)d_in[12];
    const int*   spk  = (const int*)d_in[13];
    float* out = (float*)d_out;

    char* ws = (char*)d_ws;
    size_t off = 0;
    auto alloc = [&](size_t bytes) -> char* {
        char* p = ws + off;
        off += (bytes + 255) & ~(size_t)255;
        return p;
    };
    unsigned short* wqkv_b = (unsigned short*)alloc((size_t)LN * TD * DN * 2);
    unsigned short* wo_b   = (unsigned short*)alloc((size_t)LN * DN * DN * 2);
    unsigned short* w1_b   = (unsigned short*)alloc((size_t)LN * FN * DN * 2);
    unsigned short* w2_b   = (unsigned short*)alloc((size_t)LN * DN * FN * 2);
    unsigned short* xb     = (unsigned short*)alloc((size_t)MN * DN * 2);
    unsigned short* u      = (unsigned short*)alloc((size_t)MN * FN * 2); // qkv / mlp-hidden union
    unsigned short* ob     = (unsigned short*)alloc((size_t)MN * DN * 2);
    unsigned short* projb  = (unsigned short*)alloc((size_t)MN * DN * 2);
    unsigned short* qkvb = u;
    unsigned short* hb   = u;

    // fused weight + input conversion (f32 -> bf16), one dispatch
    k_cvt_all<<<2048, 256, 0, stream>>>(Wqkv, Wo, W1, W2, te,
                                        wqkv_b, wo_b, w1_b, w2_b, xb);

    for (int l = 0; l < LN; ++l) {
        // QKV projection -> qkv (bf16): 64 x 12 tiles
        k_gemm<1, 128><<<(MN / 128) * (TD / 128), 256, 0, stream>>>(
            xb, wqkv_b + (size_t)l * TD * DN, bqkv + l * TD, qkvb,
            MN, TD, DN, TD / 128);
        // masked MFMA flash attention -> ob (bf16)
        k_attn<<<(SN / 64) * BN * HN, 256, 0, stream>>>(qkvb, spk, ob);
        // output projection -> projb (bf16): 64 x 8 tiles (BNT=64)
        k_gemm<1, 64><<<(MN / 128) * (DN / 64), 256, 0, stream>>>(
            ob, wo_b + (size_t)l * DN * DN, bo + l * DN, projb,
            MN, DN, DN, DN / 64);
        // x = LN(x + attn)
        if (l == 0)
            k_add_ln<true><<<MN / 4, 256, 0, stream>>>(
                te, projb, g1 + l * DN, be1 + l * DN, xb, nullptr);
        else
            k_add_ln<false><<<MN / 4, 256, 0, stream>>>(
                xb, projb, g1 + l * DN, be1 + l * DN, xb, nullptr);
        // MLP up + ReLU -> hb (bf16): 64 x 16 tiles
        k_gemm<2, 128><<<(MN / 128) * (FN / 128), 256, 0, stream>>>(
            xb, w1_b + (size_t)l * FN * DN, b1 + l * FN, hb,
            MN, FN, DN, FN / 128);
        // MLP down -> projb (bf16): 64 x 8 tiles (BNT=64)
        k_gemm<1, 64><<<(MN / 128) * (DN / 64), 256, 0, stream>>>(
            hb, w2_b + (size_t)l * DN * FN, b2 + l * DN, projb,
            MN, DN, FN, DN / 64);
        // x = LN(x + mlp); last layer also writes f32 d_out
        k_add_ln<false><<<MN / 4, 256, 0, stream>>>(
            xb, projb, g2 + l * DN, be2 + l * DN, xb,
            (l == LN - 1) ? out : nullptr);
    }
    (void)in_sizes; (void)n_in; (void)out_size; (void)ws_size;
}

// Round 12
// 624.134 us; speedup vs baseline: 1.0209x; 1.0209x over previous
//
#include <hip/hip_runtime.h>
#include <stdint.h>

// Problem constants
#define BN 4
#define SN 2048
#define DN 512
#define HN 8
#define LN 4
#define FN 2048
#define MN (BN * SN)        // 8192 rows
#define TD (3 * DN)         // 1536

typedef __attribute__((ext_vector_type(8))) __bf16 bf16x8;
typedef __attribute__((ext_vector_type(4))) float f32x4;
typedef __attribute__((ext_vector_type(8))) unsigned short ushortx8;

static __device__ __forceinline__ unsigned short f2bf(float f) {
    return __builtin_bit_cast(unsigned short, (__bf16)f);   // RNE via v_cvt
}
static __device__ __forceinline__ float bf2f(unsigned short h) {
    return __builtin_bit_cast(float, (uint32_t)h << 16);
}

// async global->LDS, 16B per lane; LDS dest = wave-uniform base + lane*16
static __device__ __forceinline__ void gload16(const void* g, void* l) {
    __builtin_amdgcn_global_load_lds(
        (const __attribute__((address_space(1))) void*)g,
        (__attribute__((address_space(3))) void*)l, 16, 0, 0);
}

// ---------------- fused f32 -> bf16 cast for all weights + input ----------
__global__ __launch_bounds__(256) void k_cvt_all(const float* __restrict__ Wqkv,
                                                 const float* __restrict__ Wo,
                                                 const float* __restrict__ W1,
                                                 const float* __restrict__ W2,
                                                 const float* __restrict__ te,
                                                 unsigned short* __restrict__ wqkv_b,
                                                 unsigned short* __restrict__ wo_b,
                                                 unsigned short* __restrict__ w1_b,
                                                 unsigned short* __restrict__ w2_b,
                                                 unsigned short* __restrict__ xb) {
    constexpr int G0 = LN * TD * DN / 4;
    constexpr int G1 = G0 + LN * DN * DN / 4;
    constexpr int G2 = G1 + LN * FN * DN / 4;
    constexpr int G3 = G2 + LN * DN * FN / 4;
    constexpr int G4 = G3 + MN * DN / 4;
    int i = blockIdx.x * blockDim.x + threadIdx.x;
    int stride = gridDim.x * blockDim.x;
    for (; i < G4; i += stride) {
        const float* s; unsigned short* d; int j;
        if (i < G0)      { s = Wqkv; d = wqkv_b; j = i; }
        else if (i < G1) { s = Wo;   d = wo_b;   j = i - G0; }
        else if (i < G2) { s = W1;   d = w1_b;   j = i - G1; }
        else if (i < G3) { s = W2;   d = w2_b;   j = i - G2; }
        else             { s = te;   d = xb;     j = i - G3; }
        float4 v = ((const float4*)s)[j];
        ushort4 o;
        o.x = f2bf(v.x); o.y = f2bf(v.y); o.z = f2bf(v.z); o.w = f2bf(v.w);
        ((ushort4*)d)[j] = o;
    }
}

// ---------------- GEMM: C[M,N] = A[M,K] @ B[N,K]^T + bias, bf16 out ------
// BK=32 double-buffer with COUNTED vmcnt (T4): next tile's global_load_lds
// issued before compute, raw s_barrier, s_waitcnt vmcnt(G) so the new loads
// stay in flight across the barrier (no vmcnt(0) drain).
// Granule XOR swizzle for 64B rows: granule = slot ^ ((row>>1)&3).
// MODE 1: bf16; MODE 2: bf16 + ReLU
template <int MODE, int BNT>
__global__ __launch_bounds__(256) void k_gemm(const unsigned short* __restrict__ A,
                                              const unsigned short* __restrict__ B,
                                              const float* __restrict__ bias,
                                              unsigned short* __restrict__ Cb,
                                              int M, int N, int K, int GX) {
    __shared__ __align__(16) unsigned short As[2][128][32];   // 16KB
    __shared__ __align__(16) unsigned short Bs[2][BNT][32];   // 16/8KB
    constexpr int NFR = BNT / 32;        // n-frags per wave (4 or 2)
    constexpr int BCHW = BNT / 64;       // B chunks per wave (2 or 1)

    const int t = threadIdx.x;
    const int lane = t & 63;
    const int wid = t >> 6;
    const int wm = wid >> 1, wn = wid & 1;
    const int lr = lane & 15;
    const int lg = lane >> 4;

    // XCD-aware bijective swizzle (nwg % 8 == 0 for all our shapes)
    const int nwg = gridDim.x;
    const int bid = blockIdx.x;
    const int swz = (bid & 7) * (nwg >> 3) + (bid >> 3);
    const int bx = swz % GX;
    const int by = swz / GX;

    const size_t rowA = (size_t)by * 128;
    const size_t rowB = (size_t)bx * BNT;
    const unsigned short* Ab = A + rowA * K;
    const unsigned short* Bb = B + rowB * K;

    // staging: chunk = 16 rows x 32 cols (1KB); lane -> row 16c+(lane>>2),
    // LDS slot lane&3; global granule = slot ^ ((row>>1)&3) [inverse swizzle]
    const int srow = lane >> 2;                       // 0..15
    const int sgran = (lane & 3) ^ ((srow >> 1) & 3);
    const size_t soff = (size_t)srow * K + sgran * 8;

    f32x4 acc[4][NFR] = {};
    const int nit = K >> 5;

    // prologue: stage tile 0 into buf 0
#pragma unroll
    for (int j = 0; j < 2; ++j) {
        const int c = wid * 2 + j;
        gload16(Ab + (size_t)(16 * c) * K + soff, &As[0][16 * c][0]);
    }
#pragma unroll
    for (int j = 0; j < BCHW; ++j) {
        const int c = wid * BCHW + j;
        gload16(Bb + (size_t)(16 * c) * K + soff, &Bs[0][16 * c][0]);
    }

    for (int it = 0; it < nit; ++it) {
        const int cur = it & 1;
        if (it + 1 < nit) {             // issue next-tile loads (stay in flight)
            const int k0 = (it + 1) << 5;
#pragma unroll
            for (int j = 0; j < 2; ++j) {
                const int c = wid * 2 + j;
                gload16(Ab + (size_t)(16 * c) * K + k0 + soff, &As[cur ^ 1][16 * c][0]);
            }
#pragma unroll
            for (int j = 0; j < BCHW; ++j) {
                const int c = wid * BCHW + j;
                gload16(Bb + (size_t)(16 * c) * K + k0 + soff, &Bs[cur ^ 1][16 * c][0]);
            }
            if (BNT == 128) asm volatile("s_waitcnt vmcnt(4)" ::: "memory");
            else            asm volatile("s_waitcnt vmcnt(3)" ::: "memory");
        } else {
            asm volatile("s_waitcnt vmcnt(0)" ::: "memory");
        }
        __builtin_amdgcn_s_barrier();   // cur-tile loads globally visible

        const int gp = (lg ^ ((lr >> 1) & 3)) * 8;
        bf16x8 af[4], bfr[NFR];
#pragma unroll
        for (int mi = 0; mi < 4; ++mi)
            af[mi] = *(const bf16x8*)&As[cur][wm * 64 + mi * 16 + lr][gp];
#pragma unroll
        for (int ni = 0; ni < NFR; ++ni)
            bfr[ni] = *(const bf16x8*)&Bs[cur][wn * (BNT / 2) + ni * 16 + lr][gp];
#pragma unroll
        for (int mi = 0; mi < 4; ++mi)
#pragma unroll
            for (int ni = 0; ni < NFR; ++ni)
                acc[mi][ni] = __builtin_amdgcn_mfma_f32_16x16x32_bf16(
                    af[mi], bfr[ni], acc[mi][ni], 0, 0, 0);

        __builtin_amdgcn_s_barrier();   // all reads of buf[cur] done
    }

    float bv[NFR];
#pragma unroll
    for (int ni = 0; ni < NFR; ++ni)
        bv[ni] = bias[(int)rowB + wn * (BNT / 2) + ni * 16 + lr];

#pragma unroll
    for (int mi = 0; mi < 4; ++mi) {
#pragma unroll
        for (int ni = 0; ni < NFR; ++ni) {
            int col = (int)rowB + wn * (BNT / 2) + ni * 16 + lr;
            int row0 = (int)rowA + wm * 64 + mi * 16 + lg * 4;
#pragma unroll
            for (int r = 0; r < 4; ++r) {
                float v = acc[mi][ni][r] + bv[ni];
                if (MODE == 2) v = fmaxf(v, 0.f);
                Cb[(size_t)(row0 + r) * N + col] = f2bf(v);
            }
        }
    }
}

// ---------------- MFMA flash attention, QBLK=64, no-max softmax -----------
// Round-7 structure (best measured): reg-staged K/V, XOR-swizzled
// conflict-free LDS, 4 waves, 1024 blocks, 40KB = 4 blocks/CU.
__global__ __launch_bounds__(256) void k_attn(const unsigned short* __restrict__ qkv,
                                              const int* __restrict__ spk,
                                              unsigned short* __restrict__ o) {
    __shared__ __align__(16) unsigned short Ks[2][64][64];
    __shared__ __align__(16) unsigned short Vt[2][64][64];   // Vt[d][k]
    __shared__ __align__(16) unsigned short Ps[4][16][64];

    const int t = threadIdx.x;
    const int lane = t & 63;
    const int w = t >> 6;
    const int lr = lane & 15;
    const int lg = lane >> 4;
    const int l7 = lr & 7;

    const int wg = blockIdx.x;
    const int inner = wg >> 3;
    const int bh = 4 * (wg & 7) + (inner & 3);        // XCD owns 4 (b,h) cols
    const int qtile = (SN / 64 - 1) - (inner >> 2);   // heavy tiles first
    const int b = bh >> 3;
    const int h = bh & 7;
    const int qb = qtile * 64;

    const size_t base = (size_t)b * SN * TD;
    const unsigned short* kg = qkv + base + DN + h * 64;
    const unsigned short* vg = qkv + base + 2 * DN + h * 64;

    // Q fragments (A-operand), pre-scaled by 1/sqrt(64)*log2(e)
    const float SCL = 0.125f * 1.4426950408889634f;
    const unsigned short* qptr = qkv + base + (size_t)(qb + w * 16 + lr) * TD + h * 64;
    bf16x8 aq0 = *(const bf16x8*)(qptr + lg * 8);
    bf16x8 aq1 = *(const bf16x8*)(qptr + 32 + lg * 8);
#pragma unroll
    for (int j = 0; j < 8; ++j) {
        aq0[j] = (__bf16)((float)aq0[j] * SCL);
        aq1[j] = (__bf16)((float)aq1[j] * SCL);
    }

    int sqr[4], qrow[4];
#pragma unroll
    for (int r = 0; r < 4; ++r) {
        qrow[r] = qb + w * 16 + lg * 4 + r;
        sqr[r] = spk[b * SN + qrow[r]];
    }

    // staging coords
    const int kr0 = t >> 3;              // 0..31
    const int kgr = ((t & 7) ^ (kr0 & 7)) * 8;   // swizzled granule
    const int vrow = t & 63;
    const int vd0 = (t >> 6) * 16;

    // prefetch + stage tile 0
    uint4 kra = *(const uint4*)&kg[(size_t)kr0 * TD + (t & 7) * 8];
    uint4 krb = *(const uint4*)&kg[(size_t)(kr0 + 32) * TD + (t & 7) * 8];
    ushortx8 vra = *(const ushortx8*)&vg[(size_t)vrow * TD + vd0];
    ushortx8 vrb = *(const ushortx8*)&vg[(size_t)vrow * TD + vd0 + 8];
    *(uint4*)&Ks[0][kr0][kgr] = kra;
    *(uint4*)&Ks[0][kr0 + 32][kgr] = krb;
#pragma unroll
    for (int j = 0; j < 8; ++j) {
        const int vc0 = (((vrow >> 3) ^ j) << 3) + (vrow & 7); // (vd0+j)&7 == j
        Vt[0][vd0 + j][vc0] = vra[j];
        Vt[0][vd0 + 8 + j][vc0] = vrb[j];
    }

    float lsum[4] = {0.f, 0.f, 0.f, 0.f};   // per-lane partial softmax denom
    f32x4 acc_o[4] = {};

    const int ntiles = qtile + 1;
    for (int it = 0; it < ntiles; ++it) {
        const int k0 = it * 64;
        const int cur = it & 1;
        __syncthreads();   // buf[cur] staged & visible; buf[cur^1] free

        const bool nx = (it + 1 < ntiles);
        if (nx) {          // prefetch next tile into regs (T14)
            const int kn = k0 + 64;
            kra = *(const uint4*)&kg[(size_t)(kn + kr0) * TD + (t & 7) * 8];
            krb = *(const uint4*)&kg[(size_t)(kn + kr0 + 32) * TD + (t & 7) * 8];
            vra = *(const ushortx8*)&vg[(size_t)(kn + vrow) * TD + vd0];
            vrb = *(const ushortx8*)&vg[(size_t)(kn + vrow) * TD + vd0 + 8];
        }
        int skr[4];
#pragma unroll
        for (int ni = 0; ni < 4; ++ni) skr[ni] = spk[b * SN + k0 + 16 * ni + lr];

        // QK^T (pre-scaled): S[16q][64k] in log2 domain
        f32x4 sc4[4] = {};
        __builtin_amdgcn_s_setprio(1);
#pragma unroll
        for (int ni = 0; ni < 4; ++ni) {
            bf16x8 bk0 = *(const bf16x8*)&Ks[cur][16 * ni + lr][(lg ^ l7) * 8];
            bf16x8 bk1 = *(const bf16x8*)&Ks[cur][16 * ni + lr][((lg + 4) ^ l7) * 8];
            sc4[ni] = __builtin_amdgcn_mfma_f32_16x16x32_bf16(aq0, bk0, sc4[ni], 0, 0, 0);
            sc4[ni] = __builtin_amdgcn_mfma_f32_16x16x32_bf16(aq1, bk1, sc4[ni], 0, 0, 0);
        }
        __builtin_amdgcn_s_setprio(0);

        // p = allow ? exp2(s) : 0 ; accumulate per-lane denom; stash bf16 P
        const bool diag = (it == ntiles - 1);
#pragma unroll
        for (int ni = 0; ni < 4; ++ni) {
#pragma unroll
            for (int r = 0; r < 4; ++r) {
                bool allow = (skr[ni] == sqr[r]);
                if (diag) allow = allow && (16 * ni + lr <= w * 16 + lg * 4 + r);
                float p = allow ? __builtin_amdgcn_exp2f(sc4[ni][r]) : 0.f;
                lsum[r] += p;
                const int q7 = (lg * 4 + r) & 7;
                const int pg = ((2 * ni + (lr >> 3)) ^ q7) * 8 + l7;
                Ps[w][lg * 4 + r][pg] = f2bf(p);
            }
        }

        // PV: O[16q][64d] += P[16q][64k] @ V[64k][64d]
        bf16x8 ap0 = *(const bf16x8*)&Ps[w][lr][(lg ^ l7) * 8];
        bf16x8 ap1 = *(const bf16x8*)&Ps[w][lr][((lg + 4) ^ l7) * 8];
        __builtin_amdgcn_s_setprio(1);
#pragma unroll
        for (int ni = 0; ni < 4; ++ni) {
            bf16x8 bv0 = *(const bf16x8*)&Vt[cur][16 * ni + lr][(lg ^ l7) * 8];
            bf16x8 bv1 = *(const bf16x8*)&Vt[cur][16 * ni + lr][((lg + 4) ^ l7) * 8];
            acc_o[ni] = __builtin_amdgcn_mfma_f32_16x16x32_bf16(ap0, bv0, acc_o[ni], 0, 0, 0);
            acc_o[ni] = __builtin_amdgcn_mfma_f32_16x16x32_bf16(ap1, bv1, acc_o[ni], 0, 0, 0);
        }
        __builtin_amdgcn_s_setprio(0);

        if (nx) {          // write prefetched tile into the other buffer
            const int nb = cur ^ 1;
            *(uint4*)&Ks[nb][kr0][kgr] = kra;
            *(uint4*)&Ks[nb][kr0 + 32][kgr] = krb;
#pragma unroll
            for (int j = 0; j < 8; ++j) {
                const int vc0 = (((vrow >> 3) ^ j) << 3) + (vrow & 7);
                Vt[nb][vd0 + j][vc0] = vra[j];
                Vt[nb][vd0 + 8 + j][vc0] = vrb[j];
            }
        }
    }

    // reduce denom across the 16 k-lanes (lane bits 0..3), then write O
#pragma unroll
    for (int r = 0; r < 4; ++r) {
        float s = lsum[r];
        s += __shfl_xor(s, 1);
        s += __shfl_xor(s, 2);
        s += __shfl_xor(s, 4);
        s += __shfl_xor(s, 8);
        float inv = 1.f / s;
#pragma unroll
        for (int ni = 0; ni < 4; ++ni) {
            int d = 16 * ni + lr;
            o[(size_t)(b * SN + qrow[r]) * DN + h * 64 + d] = f2bf(acc_o[ni][r] * inv);
        }
    }
}

// ---------------- residual add + LayerNorm (wave per row of 512) ----------
// bf16 residual stream; optional f32 final output.
template <bool XF32>
__global__ __launch_bounds__(256) void k_add_ln(const void* __restrict__ xin_,
                                                const unsigned short* __restrict__ dl,
                                                const float* __restrict__ g,
                                                const float* __restrict__ bta,
                                                unsigned short* __restrict__ xb,
                                                float* __restrict__ fout) {
    const int row = blockIdx.x * 4 + (threadIdx.x >> 6);
    const int lane = threadIdx.x & 63;
    const size_t off = (size_t)row * DN + lane * 8;
    const int c0 = lane * 8;

    float v[8];
    if (XF32) {
        const float* xin = (const float*)xin_;
        float4 a0 = *(const float4*)&xin[off];
        float4 a1 = *(const float4*)&xin[off + 4];
        v[0] = a0.x; v[1] = a0.y; v[2] = a0.z; v[3] = a0.w;
        v[4] = a1.x; v[5] = a1.y; v[6] = a1.z; v[7] = a1.w;
    } else {
        ushortx8 xa = *(const ushortx8*)&((const unsigned short*)xin_)[off];
#pragma unroll
        for (int i = 0; i < 8; ++i) v[i] = bf2f(xa[i]);
    }
    ushortx8 dd = *(const ushortx8*)&dl[off];
#pragma unroll
    for (int i = 0; i < 8; ++i) v[i] += bf2f(dd[i]);

    float s1 = 0.f, s2 = 0.f;
#pragma unroll
    for (int i = 0; i < 8; ++i) { s1 += v[i]; s2 += v[i] * v[i]; }
#pragma unroll
    for (int msk = 32; msk; msk >>= 1) {
        s1 += __shfl_xor(s1, msk);
        s2 += __shfl_xor(s2, msk);
    }
    const float mean = s1 * (1.f / 512.f);
    const float var = s2 * (1.f / 512.f) - mean * mean;
    const float rs = rsqrtf(var + 1e-5f);

    float4 g0 = *(const float4*)&g[c0];
    float4 g1 = *(const float4*)&g[c0 + 4];
    float4 b0 = *(const float4*)&bta[c0];
    float4 b1 = *(const float4*)&bta[c0 + 4];
    float gg[8] = {g0.x, g0.y, g0.z, g0.w, g1.x, g1.y, g1.z, g1.w};
    float bb[8] = {b0.x, b0.y, b0.z, b0.w, b1.x, b1.y, b1.z, b1.w};

    float y[8];
    ushortx8 ub;
#pragma unroll
    for (int i = 0; i < 8; ++i) {
        y[i] = (v[i] - mean) * rs * gg[i] + bb[i];
        ub[i] = f2bf(y[i]);
    }
    *(ushortx8*)&xb[off] = ub;
    if (fout) {
        *(float4*)&fout[off] = make_float4(y[0], y[1], y[2], y[3]);
        *(float4*)&fout[off + 4] = make_float4(y[4], y[5], y[6], y[7]);
    }
}

extern "C" void kernel_launch(void* const* d_in, const int* in_sizes, int n_in,
                              void* d_out, int out_size, void* d_ws, size_t ws_size,
                              hipStream_t stream) {
    const float* te   = (const float*)d_in[0];
    const float* Wqkv = (const float*)d_in[1];
    const float* bqkv = (const float*)d_in[2];
    const float* Wo   = (const float*)d_in[3];
    const float* bo   = (const float*)d_in[4];
    const float* W1   = (const float*)d_in[5];
    const float* b1   = (const float*)d_in[6];
    const float* W2   = (const float*)d_in[7];
    const float* b2   = (const float*)d_in[8];
    const float* g1   = (const float*)d_in[9];
    const float* be1  = (const float*)d_in[10];
    const float* g2   = (const float*)d_in[11];
    const float* be2  = (const float*)d_in[12];
    const int*   spk  = (const int*)d_in[13];
    float* out = (float*)d_out;

    char* ws = (char*)d_ws;
    size_t off = 0;
    auto alloc = [&](size_t bytes) -> char* {
        char* p = ws + off;
        off += (bytes + 255) & ~(size_t)255;
        return p;
    };
    unsigned short* wqkv_b = (unsigned short*)alloc((size_t)LN * TD * DN * 2);
    unsigned short* wo_b   = (unsigned short*)alloc((size_t)LN * DN * DN * 2);
    unsigned short* w1_b   = (unsigned short*)alloc((size_t)LN * FN * DN * 2);
    unsigned short* w2_b   = (unsigned short*)alloc((size_t)LN * DN * FN * 2);
    unsigned short* xb     = (unsigned short*)alloc((size_t)MN * DN * 2);
    unsigned short* u      = (unsigned short*)alloc((size_t)MN * FN * 2); // qkv / mlp-hidden union
    unsigned short* ob     = (unsigned short*)alloc((size_t)MN * DN * 2);
    unsigned short* projb  = (unsigned short*)alloc((size_t)MN * DN * 2);
    unsigned short* qkvb = u;
    unsigned short* hb   = u;

    // fused weight + input conversion (f32 -> bf16), one dispatch
    k_cvt_all<<<2048, 256, 0, stream>>>(Wqkv, Wo, W1, W2, te,
                                        wqkv_b, wo_b, w1_b, w2_b, xb);

    for (int l = 0; l < LN; ++l) {
        // QKV projection -> qkv (bf16): 64 x 12 tiles
        k_gemm<1, 128><<<(MN / 128) * (TD / 128), 256, 0, stream>>>(
            xb, wqkv_b + (size_t)l * TD * DN, bqkv + l * TD, qkvb,
            MN, TD, DN, TD / 128);
        // masked MFMA flash attention -> ob (bf16)
        k_attn<<<(SN / 64) * BN * HN, 256, 0, stream>>>(qkvb, spk, ob);
        // output projection -> projb (bf16): 64 x 8 tiles (BNT=64)
        k_gemm<1, 64><<<(MN / 128) * (DN / 64), 256, 0, stream>>>(
            ob, wo_b + (size_t)l * DN * DN, bo + l * DN, projb,
            MN, DN, DN, DN / 64);
        // x = LN(x + attn)
        if (l == 0)
            k_add_ln<true><<<MN / 4, 256, 0, stream>>>(
                te, projb, g1 + l * DN, be1 + l * DN, xb, nullptr);
        else
            k_add_ln<false><<<MN / 4, 256, 0, stream>>>(
                xb, projb, g1 + l * DN, be1 + l * DN, xb, nullptr);
        // MLP up + ReLU -> hb (bf16): 64 x 16 tiles
        k_gemm<2, 128><<<(MN / 128) * (FN / 128), 256, 0, stream>>>(
            xb, w1_b + (size_t)l * FN * DN, b1 + l * FN, hb,
            MN, FN, DN, FN / 128);
        // MLP down -> projb (bf16): 64 x 8 tiles (BNT=64)
        k_gemm<1, 64><<<(MN / 128) * (DN / 64), 256, 0, stream>>>(
            hb, w2_b + (size_t)l * DN * FN, b2 + l * DN, projb,
            MN, DN, FN, DN / 64);
        // x = LN(x + mlp); last layer also writes f32 d_out
        k_add_ln<false><<<MN / 4, 256, 0, stream>>>(
            xb, projb, g2 + l * DN, be2 + l * DN, xb,
            (l == LN - 1) ? out : nullptr);
    }
    (void)in_sizes; (void)n_in; (void)out_size; (void)ws_size;
}

// Round 13
// 579.570 us; speedup vs baseline: 1.0994x; 1.0769x over previous
//
#include <hip/hip_runtime.h>
#include <stdint.h>

// Problem constants
#define BN 4
#define SN 2048
#define DN 512
#define HN 8
#define LN 4
#define FN 2048
#define MN (BN * SN)        // 8192 rows
#define TD (3 * DN)         // 1536

typedef __attribute__((ext_vector_type(8))) __bf16 bf16x8;
typedef __attribute__((ext_vector_type(4))) float f32x4;
typedef __attribute__((ext_vector_type(8))) unsigned short ushortx8;

static __device__ __forceinline__ unsigned short f2bf(float f) {
    return __builtin_bit_cast(unsigned short, (__bf16)f);   // RNE via v_cvt
}
static __device__ __forceinline__ float bf2f(unsigned short h) {
    return __builtin_bit_cast(float, (uint32_t)h << 16);
}

// async global->LDS, 16B per lane; LDS dest = wave-uniform base + lane*16
static __device__ __forceinline__ void gload16(const void* g, void* l) {
    __builtin_amdgcn_global_load_lds(
        (const __attribute__((address_space(1))) void*)g,
        (__attribute__((address_space(3))) void*)l, 16, 0, 0);
}

// ---------------- fused f32 -> bf16 cast for all weights + input ----------
__global__ __launch_bounds__(256) void k_cvt_all(const float* __restrict__ Wqkv,
                                                 const float* __restrict__ Wo,
                                                 const float* __restrict__ W1,
                                                 const float* __restrict__ W2,
                                                 const float* __restrict__ te,
                                                 unsigned short* __restrict__ wqkv_b,
                                                 unsigned short* __restrict__ wo_b,
                                                 unsigned short* __restrict__ w1_b,
                                                 unsigned short* __restrict__ w2_b,
                                                 unsigned short* __restrict__ xb) {
    constexpr int G0 = LN * TD * DN / 4;
    constexpr int G1 = G0 + LN * DN * DN / 4;
    constexpr int G2 = G1 + LN * FN * DN / 4;
    constexpr int G3 = G2 + LN * DN * FN / 4;
    constexpr int G4 = G3 + MN * DN / 4;
    int i = blockIdx.x * blockDim.x + threadIdx.x;
    int stride = gridDim.x * blockDim.x;
    for (; i < G4; i += stride) {
        const float* s; unsigned short* d; int j;
        if (i < G0)      { s = Wqkv; d = wqkv_b; j = i; }
        else if (i < G1) { s = Wo;   d = wo_b;   j = i - G0; }
        else if (i < G2) { s = W1;   d = w1_b;   j = i - G1; }
        else if (i < G3) { s = W2;   d = w2_b;   j = i - G2; }
        else             { s = te;   d = xb;     j = i - G3; }
        float4 v = ((const float4*)s)[j];
        ushort4 o;
        o.x = f2bf(v.x); o.y = f2bf(v.y); o.z = f2bf(v.z); o.w = f2bf(v.w);
        ((ushort4*)d)[j] = o;
    }
}

// ---------------- GEMM: C[M,N] = A[M,K] @ B[N,K]^T + bias, bf16 out ------
// Round-9 structure (best measured): BK=64 single buffer,
// global_load_lds w=16, XOR granule swizzle (slot ^ row&7) both sides.
// Tile BMT x BNT; 4 waves, each covering (BMT/2)x(BNT/2).
// MODE 1: bf16; MODE 2: bf16 + ReLU
template <int MODE, int BMT, int BNT>
__global__ __launch_bounds__(256) void k_gemm(const unsigned short* __restrict__ A,
                                              const unsigned short* __restrict__ B,
                                              const float* __restrict__ bias,
                                              unsigned short* __restrict__ Cb,
                                              int M, int N, int K, int GX) {
    __shared__ __align__(16) unsigned short As[BMT][64];
    __shared__ __align__(16) unsigned short Bs[BNT][64];
    constexpr int MFR = BMT / 32;        // m-frags per wave (4 or 2)
    constexpr int NFR = BNT / 32;        // n-frags per wave (4 or 2)

    const int t = threadIdx.x;
    const int lane = t & 63;
    const int wid = t >> 6;
    const int wm = wid >> 1, wn = wid & 1;
    const int lr = lane & 15;
    const int lg = lane >> 4;

    // XCD-aware bijective swizzle (nwg % 8 == 0 for all our shapes)
    const int nwg = gridDim.x;
    const int bid = blockIdx.x;
    const int swz = (bid & 7) * (nwg >> 3) + (bid >> 3);
    const int bx = swz % GX;
    const int by = swz / GX;

    const size_t rowA = (size_t)by * BMT;
    const size_t rowB = (size_t)bx * BNT;
    const unsigned short* Ab = A + rowA * K;
    const unsigned short* Bb = B + rowB * K;

    // staging: chunk = 8 rows x 64 cols (1KB); lane -> row c*8 + (lane>>3),
    // LDS slot lane&7; global granule = slot ^ (row&7)  [inverse swizzle]
    const int srow = lane >> 3;
    const int sgran = (lane & 7) ^ srow;

    f32x4 acc[MFR][NFR] = {};

    for (int k0 = 0; k0 < K; k0 += 64) {
        __syncthreads();
#pragma unroll
        for (int j = 0; j < MFR; ++j) {  // A: BMT/8 chunks over 4 waves
            const int c = wid * MFR + j;
            const size_t goff = (size_t)(8 * c + srow) * K + k0 + sgran * 8;
            gload16(Ab + goff, &As[8 * c][0]);
        }
#pragma unroll
        for (int j = 0; j < NFR; ++j) {  // B: BNT/8 chunks over 4 waves
            const int c = wid * NFR + j;
            const size_t goff = (size_t)(8 * c + srow) * K + k0 + sgran * 8;
            gload16(Bb + goff, &Bs[8 * c][0]);
        }
        __syncthreads();

#pragma unroll
        for (int h = 0; h < 2; ++h) {
            const int gp = (h * 4 + lg) ^ (lr & 7);
            bf16x8 af[MFR], bfr[NFR];
#pragma unroll
            for (int mi = 0; mi < MFR; ++mi)
                af[mi] = *(const bf16x8*)&As[wm * (BMT / 2) + mi * 16 + lr][gp * 8];
#pragma unroll
            for (int ni = 0; ni < NFR; ++ni)
                bfr[ni] = *(const bf16x8*)&Bs[wn * (BNT / 2) + ni * 16 + lr][gp * 8];
#pragma unroll
            for (int mi = 0; mi < MFR; ++mi)
#pragma unroll
                for (int ni = 0; ni < NFR; ++ni)
                    acc[mi][ni] = __builtin_amdgcn_mfma_f32_16x16x32_bf16(
                        af[mi], bfr[ni], acc[mi][ni], 0, 0, 0);
        }
    }

    float bv[NFR];
#pragma unroll
    for (int ni = 0; ni < NFR; ++ni)
        bv[ni] = bias[(int)rowB + wn * (BNT / 2) + ni * 16 + lr];

#pragma unroll
    for (int mi = 0; mi < MFR; ++mi) {
#pragma unroll
        for (int ni = 0; ni < NFR; ++ni) {
            int col = (int)rowB + wn * (BNT / 2) + ni * 16 + lr;
            int row0 = (int)rowA + wm * (BMT / 2) + mi * 16 + lg * 4;
#pragma unroll
            for (int r = 0; r < 4; ++r) {
                float v = acc[mi][ni][r] + bv[ni];
                if (MODE == 2) v = fmaxf(v, 0.f);
                Cb[(size_t)(row0 + r) * N + col] = f2bf(v);
            }
        }
    }
}

// ---------------- MFMA flash attention, QBLK=64, no-max softmax -----------
// Best measured structure: reg-staged K/V, XOR-swizzled conflict-free LDS,
// 4 waves, 1024 blocks, 40KB = 4 blocks/CU, setprio on MFMA clusters.
__global__ __launch_bounds__(256) void k_attn(const unsigned short* __restrict__ qkv,
                                              const int* __restrict__ spk,
                                              unsigned short* __restrict__ o) {
    __shared__ __align__(16) unsigned short Ks[2][64][64];
    __shared__ __align__(16) unsigned short Vt[2][64][64];   // Vt[d][k]
    __shared__ __align__(16) unsigned short Ps[4][16][64];

    const int t = threadIdx.x;
    const int lane = t & 63;
    const int w = t >> 6;
    const int lr = lane & 15;
    const int lg = lane >> 4;
    const int l7 = lr & 7;

    const int wg = blockIdx.x;
    const int inner = wg >> 3;
    const int bh = 4 * (wg & 7) + (inner & 3);        // XCD owns 4 (b,h) cols
    const int qtile = (SN / 64 - 1) - (inner >> 2);   // heavy tiles first
    const int b = bh >> 3;
    const int h = bh & 7;
    const int qb = qtile * 64;

    const size_t base = (size_t)b * SN * TD;
    const unsigned short* kg = qkv + base + DN + h * 64;
    const unsigned short* vg = qkv + base + 2 * DN + h * 64;

    // Q fragments (A-operand), pre-scaled by 1/sqrt(64)*log2(e)
    const float SCL = 0.125f * 1.4426950408889634f;
    const unsigned short* qptr = qkv + base + (size_t)(qb + w * 16 + lr) * TD + h * 64;
    bf16x8 aq0 = *(const bf16x8*)(qptr + lg * 8);
    bf16x8 aq1 = *(const bf16x8*)(qptr + 32 + lg * 8);
#pragma unroll
    for (int j = 0; j < 8; ++j) {
        aq0[j] = (__bf16)((float)aq0[j] * SCL);
        aq1[j] = (__bf16)((float)aq1[j] * SCL);
    }

    int sqr[4], qrow[4];
#pragma unroll
    for (int r = 0; r < 4; ++r) {
        qrow[r] = qb + w * 16 + lg * 4 + r;
        sqr[r] = spk[b * SN + qrow[r]];
    }

    // staging coords
    const int kr0 = t >> 3;              // 0..31
    const int kgr = ((t & 7) ^ (kr0 & 7)) * 8;   // swizzled granule
    const int vrow = t & 63;
    const int vd0 = (t >> 6) * 16;

    // prefetch + stage tile 0
    uint4 kra = *(const uint4*)&kg[(size_t)kr0 * TD + (t & 7) * 8];
    uint4 krb = *(const uint4*)&kg[(size_t)(kr0 + 32) * TD + (t & 7) * 8];
    ushortx8 vra = *(const ushortx8*)&vg[(size_t)vrow * TD + vd0];
    ushortx8 vrb = *(const ushortx8*)&vg[(size_t)vrow * TD + vd0 + 8];
    *(uint4*)&Ks[0][kr0][kgr] = kra;
    *(uint4*)&Ks[0][kr0 + 32][kgr] = krb;
#pragma unroll
    for (int j = 0; j < 8; ++j) {
        const int vc0 = (((vrow >> 3) ^ j) << 3) + (vrow & 7); // (vd0+j)&7 == j
        Vt[0][vd0 + j][vc0] = vra[j];
        Vt[0][vd0 + 8 + j][vc0] = vrb[j];
    }

    float lsum[4] = {0.f, 0.f, 0.f, 0.f};   // per-lane partial softmax denom
    f32x4 acc_o[4] = {};

    const int ntiles = qtile + 1;
    for (int it = 0; it < ntiles; ++it) {
        const int k0 = it * 64;
        const int cur = it & 1;
        __syncthreads();   // buf[cur] staged & visible; buf[cur^1] free

        const bool nx = (it + 1 < ntiles);
        if (nx) {          // prefetch next tile into regs (T14)
            const int kn = k0 + 64;
            kra = *(const uint4*)&kg[(size_t)(kn + kr0) * TD + (t & 7) * 8];
            krb = *(const uint4*)&kg[(size_t)(kn + kr0 + 32) * TD + (t & 7) * 8];
            vra = *(const ushortx8*)&vg[(size_t)(kn + vrow) * TD + vd0];
            vrb = *(const ushortx8*)&vg[(size_t)(kn + vrow) * TD + vd0 + 8];
        }
        int skr[4];
#pragma unroll
        for (int ni = 0; ni < 4; ++ni) skr[ni] = spk[b * SN + k0 + 16 * ni + lr];

        // QK^T (pre-scaled): S[16q][64k] in log2 domain
        f32x4 sc4[4] = {};
        __builtin_amdgcn_s_setprio(1);
#pragma unroll
        for (int ni = 0; ni < 4; ++ni) {
            bf16x8 bk0 = *(const bf16x8*)&Ks[cur][16 * ni + lr][(lg ^ l7) * 8];
            bf16x8 bk1 = *(const bf16x8*)&Ks[cur][16 * ni + lr][((lg + 4) ^ l7) * 8];
            sc4[ni] = __builtin_amdgcn_mfma_f32_16x16x32_bf16(aq0, bk0, sc4[ni], 0, 0, 0);
            sc4[ni] = __builtin_amdgcn_mfma_f32_16x16x32_bf16(aq1, bk1, sc4[ni], 0, 0, 0);
        }
        __builtin_amdgcn_s_setprio(0);

        // p = allow ? exp2(s) : 0 ; accumulate per-lane denom; stash bf16 P
        const bool diag = (it == ntiles - 1);
#pragma unroll
        for (int ni = 0; ni < 4; ++ni) {
#pragma unroll
            for (int r = 0; r < 4; ++r) {
                bool allow = (skr[ni] == sqr[r]);
                if (diag) allow = allow && (16 * ni + lr <= w * 16 + lg * 4 + r);
                float p = allow ? __builtin_amdgcn_exp2f(sc4[ni][r]) : 0.f;
                lsum[r] += p;
                const int q7 = (lg * 4 + r) & 7;
                const int pg = ((2 * ni + (lr >> 3)) ^ q7) * 8 + l7;
                Ps[w][lg * 4 + r][pg] = f2bf(p);
            }
        }

        // PV: O[16q][64d] += P[16q][64k] @ V[64k][64d]
        bf16x8 ap0 = *(const bf16x8*)&Ps[w][lr][(lg ^ l7) * 8];
        bf16x8 ap1 = *(const bf16x8*)&Ps[w][lr][((lg + 4) ^ l7) * 8];
        __builtin_amdgcn_s_setprio(1);
#pragma unroll
        for (int ni = 0; ni < 4; ++ni) {
            bf16x8 bv0 = *(const bf16x8*)&Vt[cur][16 * ni + lr][(lg ^ l7) * 8];
            bf16x8 bv1 = *(const bf16x8*)&Vt[cur][16 * ni + lr][((lg + 4) ^ l7) * 8];
            acc_o[ni] = __builtin_amdgcn_mfma_f32_16x16x32_bf16(ap0, bv0, acc_o[ni], 0, 0, 0);
            acc_o[ni] = __builtin_amdgcn_mfma_f32_16x16x32_bf16(ap1, bv1, acc_o[ni], 0, 0, 0);
        }
        __builtin_amdgcn_s_setprio(0);

        if (nx) {          // write prefetched tile into the other buffer
            const int nb = cur ^ 1;
            *(uint4*)&Ks[nb][kr0][kgr] = kra;
            *(uint4*)&Ks[nb][kr0 + 32][kgr] = krb;
#pragma unroll
            for (int j = 0; j < 8; ++j) {
                const int vc0 = (((vrow >> 3) ^ j) << 3) + (vrow & 7);
                Vt[nb][vd0 + j][vc0] = vra[j];
                Vt[nb][vd0 + 8 + j][vc0] = vrb[j];
            }
        }
    }

    // reduce denom across the 16 k-lanes (lane bits 0..3), then write O
#pragma unroll
    for (int r = 0; r < 4; ++r) {
        float s = lsum[r];
        s += __shfl_xor(s, 1);
        s += __shfl_xor(s, 2);
        s += __shfl_xor(s, 4);
        s += __shfl_xor(s, 8);
        float inv = 1.f / s;
#pragma unroll
        for (int ni = 0; ni < 4; ++ni) {
            int d = 16 * ni + lr;
            o[(size_t)(b * SN + qrow[r]) * DN + h * 64 + d] = f2bf(acc_o[ni][r] * inv);
        }
    }
}

// ---------------- residual add + LayerNorm (wave per row of 512) ----------
// bf16 residual stream; last layer writes ONLY the f32 output.
template <bool XF32>
__global__ __launch_bounds__(256) void k_add_ln(const void* __restrict__ xin_,
                                                const unsigned short* __restrict__ dl,
                                                const float* __restrict__ g,
                                                const float* __restrict__ bta,
                                                unsigned short* __restrict__ xb,
                                                float* __restrict__ fout) {
    const int row = blockIdx.x * 4 + (threadIdx.x >> 6);
    const int lane = threadIdx.x & 63;
    const size_t off = (size_t)row * DN + lane * 8;
    const int c0 = lane * 8;

    float v[8];
    if (XF32) {
        const float* xin = (const float*)xin_;
        float4 a0 = *(const float4*)&xin[off];
        float4 a1 = *(const float4*)&xin[off + 4];
        v[0] = a0.x; v[1] = a0.y; v[2] = a0.z; v[3] = a0.w;
        v[4] = a1.x; v[5] = a1.y; v[6] = a1.z; v[7] = a1.w;
    } else {
        ushortx8 xa = *(const ushortx8*)&((const unsigned short*)xin_)[off];
#pragma unroll
        for (int i = 0; i < 8; ++i) v[i] = bf2f(xa[i]);
    }
    ushortx8 dd = *(const ushortx8*)&dl[off];
#pragma unroll
    for (int i = 0; i < 8; ++i) v[i] += bf2f(dd[i]);

    float s1 = 0.f, s2 = 0.f;
#pragma unroll
    for (int i = 0; i < 8; ++i) { s1 += v[i]; s2 += v[i] * v[i]; }
#pragma unroll
    for (int msk = 32; msk; msk >>= 1) {
        s1 += __shfl_xor(s1, msk);
        s2 += __shfl_xor(s2, msk);
    }
    const float mean = s1 * (1.f / 512.f);
    const float var = s2 * (1.f / 512.f) - mean * mean;
    const float rs = rsqrtf(var + 1e-5f);

    float4 g0 = *(const float4*)&g[c0];
    float4 g1 = *(const float4*)&g[c0 + 4];
    float4 b0 = *(const float4*)&bta[c0];
    float4 b1 = *(const float4*)&bta[c0 + 4];
    float gg[8] = {g0.x, g0.y, g0.z, g0.w, g1.x, g1.y, g1.z, g1.w};
    float bb[8] = {b0.x, b0.y, b0.z, b0.w, b1.x, b1.y, b1.z, b1.w};

    float y[8];
#pragma unroll
    for (int i = 0; i < 8; ++i)
        y[i] = (v[i] - mean) * rs * gg[i] + bb[i];

    if (fout) {
        *(float4*)&fout[off] = make_float4(y[0], y[1], y[2], y[3]);
        *(float4*)&fout[off + 4] = make_float4(y[4], y[5], y[6], y[7]);
    } else {
        ushortx8 ub;
#pragma unroll
        for (int i = 0; i < 8; ++i) ub[i] = f2bf(y[i]);
        *(ushortx8*)&xb[off] = ub;
    }
}

extern "C" void kernel_launch(void* const* d_in, const int* in_sizes, int n_in,
                              void* d_out, int out_size, void* d_ws, size_t ws_size,
                              hipStream_t stream) {
    const float* te   = (const float*)d_in[0];
    const float* Wqkv = (const float*)d_in[1];
    const float* bqkv = (const float*)d_in[2];
    const float* Wo   = (const float*)d_in[3];
    const float* bo   = (const float*)d_in[4];
    const float* W1   = (const float*)d_in[5];
    const float* b1   = (const float*)d_in[6];
    const float* W2   = (const float*)d_in[7];
    const float* b2   = (const float*)d_in[8];
    const float* g1   = (const float*)d_in[9];
    const float* be1  = (const float*)d_in[10];
    const float* g2   = (const float*)d_in[11];
    const float* be2  = (const float*)d_in[12];
    const int*   spk  = (const int*)d_in[13];
    float* out = (float*)d_out;

    char* ws = (char*)d_ws;
    size_t off = 0;
    auto alloc = [&](size_t bytes) -> char* {
        char* p = ws + off;
        off += (bytes + 255) & ~(size_t)255;
        return p;
    };
    unsigned short* wqkv_b = (unsigned short*)alloc((size_t)LN * TD * DN * 2);
    unsigned short* wo_b   = (unsigned short*)alloc((size_t)LN * DN * DN * 2);
    unsigned short* w1_b   = (unsigned short*)alloc((size_t)LN * FN * DN * 2);
    unsigned short* w2_b   = (unsigned short*)alloc((size_t)LN * DN * FN * 2);
    unsigned short* xb     = (unsigned short*)alloc((size_t)MN * DN * 2);
    unsigned short* u      = (unsigned short*)alloc((size_t)MN * FN * 2); // qkv / mlp-hidden union
    unsigned short* ob     = (unsigned short*)alloc((size_t)MN * DN * 2);
    unsigned short* projb  = (unsigned short*)alloc((size_t)MN * DN * 2);
    unsigned short* qkvb = u;
    unsigned short* hb   = u;

    // fused weight + input conversion (f32 -> bf16), one dispatch
    k_cvt_all<<<2048, 256, 0, stream>>>(Wqkv, Wo, W1, W2, te,
                                        wqkv_b, wo_b, w1_b, w2_b, xb);

    for (int l = 0; l < LN; ++l) {
        // QKV projection -> qkv (bf16): 128x128 tiles, 768 blocks (3/CU)
        k_gemm<1, 128, 128><<<(MN / 128) * (TD / 128), 256, 0, stream>>>(
            xb, wqkv_b + (size_t)l * TD * DN, bqkv + l * TD, qkvb,
            MN, TD, DN, TD / 128);
        // masked MFMA flash attention -> ob (bf16)
        k_attn<<<(SN / 64) * BN * HN, 256, 0, stream>>>(qkvb, spk, ob);
        // output projection -> projb (bf16): 64x64 tiles, 1024 blocks (4/CU)
        k_gemm<1, 64, 64><<<(MN / 64) * (DN / 64), 256, 0, stream>>>(
            ob, wo_b + (size_t)l * DN * DN, bo + l * DN, projb,
            MN, DN, DN, DN / 64);
        // x = LN(x + attn)
        if (l == 0)
            k_add_ln<true><<<MN / 4, 256, 0, stream>>>(
                te, projb, g1 + l * DN, be1 + l * DN, xb, nullptr);
        else
            k_add_ln<false><<<MN / 4, 256, 0, stream>>>(
                xb, projb, g1 + l * DN, be1 + l * DN, xb, nullptr);
        // MLP up + ReLU -> hb (bf16): 128x128 tiles, 1024 blocks (4/CU)
        k_gemm<2, 128, 128><<<(MN / 128) * (FN / 128), 256, 0, stream>>>(
            xb, w1_b + (size_t)l * FN * DN, b1 + l * FN, hb,
            MN, FN, DN, FN / 128);
        // MLP down -> projb (bf16): 64x64 tiles, 1024 blocks (4/CU)
        k_gemm<1, 64, 64><<<(MN / 64) * (DN / 64), 256, 0, stream>>>(
            hb, w2_b + (size_t)l * DN * FN, b2 + l * DN, projb,
            MN, DN, FN, DN / 64);
        // x = LN(x + mlp); last layer writes ONLY f32 d_out
        k_add_ln<false><<<MN / 4, 256, 0, stream>>>(
            xb, projb, g2 + l * DN, be2 + l * DN, xb,
            (l == LN - 1) ? out : nullptr);
    }
    (void)in_sizes; (void)n_in; (void)out_size; (void)ws_size;
}